// Round 1
// baseline (564.090 us; speedup 1.0000x reference)
//
#include <hip/hip_runtime.h>
#include <hip/hip_bf16.h>

#define B_   64
#define CIN  256
#define COUT 512
#define S_   4096
#define HID  64
#define KEXP 4

typedef float f32x4 __attribute__((ext_vector_type(4)));
typedef short bf16x8 __attribute__((ext_vector_type(8)));

static __device__ __forceinline__ unsigned short f2bf(float f) {
    union { float f; unsigned u; } c; c.f = f;
    unsigned r = c.u + 0x7FFFu + ((c.u >> 16) & 1u);
    return (unsigned short)(r >> 16);
}

// ---------------- K1: pooled[b,c] = mean_s x[b,c,s] ----------------
__global__ __launch_bounds__(256) void k_pool(const float* __restrict__ x,
                                              float* __restrict__ pooled) {
    int row = blockIdx.x;                       // b*CIN + c
    const float* p = x + (size_t)row * S_;
    int t = threadIdx.x;
    float s = 0.f;
#pragma unroll
    for (int j = 0; j < 4; ++j) {
        float4 v = *(const float4*)(p + (size_t)(j * 256 + t) * 4);
        s += v.x + v.y + v.z + v.w;
    }
    for (int off = 32; off; off >>= 1) s += __shfl_down(s, off);
    __shared__ float ls[4];
    if ((t & 63) == 0) ls[t >> 6] = s;
    __syncthreads();
    if (t == 0) pooled[row] = (ls[0] + ls[1] + ls[2] + ls[3]) * (1.f / S_);
}

// ---------------- K2: attention weights + mixed bias ----------------
__global__ __launch_bounds__(64) void k_att(const float* __restrict__ pooled,
                                            const float* __restrict__ w1,
                                            const float* __restrict__ w2,
                                            const float* __restrict__ b2,
                                            const float* __restrict__ conv_b,
                                            float* __restrict__ att_out,
                                            float* __restrict__ bb_out) {
    int b = blockIdx.x, t = threadIdx.x;
    __shared__ float pl[CIN];
    __shared__ float hl[HID];
    __shared__ float satt[KEXP];
    for (int j = t; j < CIN; j += 64) pl[j] = pooled[b * CIN + j];
    __syncthreads();
    float acc = 0.f;
    const float* w1r = w1 + t * CIN;
#pragma unroll 4
    for (int c = 0; c < CIN; c += 4) {
        float4 w = *(const float4*)(w1r + c);
        acc += w.x * pl[c] + w.y * pl[c + 1] + w.z * pl[c + 2] + w.w * pl[c + 3];
    }
    hl[t] = fmaxf(acc, 0.f);
    __syncthreads();
    if (t < KEXP) {
        float a = 0.f;
        for (int j = 0; j < HID; ++j) a += hl[j] * w2[t * HID + j];
        satt[t] = (a + b2[t]) * (1.0f / 30.0f);
    }
    __syncthreads();
    if (t == 0) {
        float m = fmaxf(fmaxf(satt[0], satt[1]), fmaxf(satt[2], satt[3]));
        float e0 = expf(satt[0] - m), e1 = expf(satt[1] - m);
        float e2 = expf(satt[2] - m), e3 = expf(satt[3] - m);
        float inv = 1.f / (e0 + e1 + e2 + e3);
        satt[0] = e0 * inv; satt[1] = e1 * inv; satt[2] = e2 * inv; satt[3] = e3 * inv;
        for (int k = 0; k < KEXP; ++k) att_out[b * KEXP + k] = satt[k];
    }
    __syncthreads();
    for (int o = t; o < COUT; o += 64) {
        float v = 0.f;
#pragma unroll
        for (int k = 0; k < KEXP; ++k) v += satt[k] * conv_b[k * COUT + o];
        bb_out[b * COUT + o] = v;
    }
}

// ---------------- K2b: Wb[b] = sum_k att[b,k] conv_w[k]  (bf16 to ws) ----------------
__global__ __launch_bounds__(256) void k_wb(const float* __restrict__ conv_w,
                                            const float* __restrict__ att,
                                            unsigned short* __restrict__ wb) {
    int bid = blockIdx.x;
    int b = bid >> 5, o0 = (bid & 31) * 16;
    int t = threadIdx.x;
    int o = o0 + (t >> 4);
    int i0 = (t & 15) * 16;
    float ak[KEXP];
#pragma unroll
    for (int k = 0; k < KEXP; ++k) ak[k] = att[b * KEXP + k];
    float acc[16];
#pragma unroll
    for (int j = 0; j < 16; ++j) acc[j] = 0.f;
#pragma unroll
    for (int k = 0; k < KEXP; ++k) {
        const float* src = conv_w + ((size_t)(k * COUT + o)) * CIN + i0;
#pragma unroll
        for (int j4 = 0; j4 < 4; ++j4) {
            float4 v = *(const float4*)(src + j4 * 4);
            acc[j4 * 4 + 0] += ak[k] * v.x;
            acc[j4 * 4 + 1] += ak[k] * v.y;
            acc[j4 * 4 + 2] += ak[k] * v.z;
            acc[j4 * 4 + 3] += ak[k] * v.w;
        }
    }
    unsigned short us[16];
#pragma unroll
    for (int j = 0; j < 16; ++j) us[j] = f2bf(acc[j]);
    unsigned short* dst = wb + (size_t)(b * COUT + o) * CIN + i0;
    *(uint4*)(dst) = *(const uint4*)(us);
    *(uint4*)(dst + 8) = *(const uint4*)(us + 8);
}

// ---------------- K3: y[b] = Wb[b] @ x[b] + bb  (bf16 MFMA, fp32 out) ----------------
#define BM 128
#define BN 128
#define ASTR 264   // padded LDS row stride in elems (264*2B = 528B -> bank spread)

__global__ __launch_bounds__(256, 2) void k_gemm(const float* __restrict__ x,
                                                 const unsigned short* __restrict__ wb,
                                                 const float* __restrict__ bb,
                                                 float* __restrict__ out) {
    __shared__ unsigned short lds_a[BM * ASTR];

    int bid = blockIdx.x;
    // XCD-aware swizzle: batch b's 128 tiles all land on XCD (b&7)
    int batch = (bid & 7) + 8 * (bid >> 10);
    int tile = (bid >> 3) & 127;
    int m0 = (tile & 3) * BM;
    int n0 = (tile >> 2) * BN;

    int t = threadIdx.x;
    // stage full A tile [128 rows x 256 K] bf16 into padded LDS
    {
        int row = t >> 1, half = t & 1;
        const unsigned short* src =
            wb + (size_t)(batch * COUT + m0 + row) * CIN + half * 128;
        unsigned short* dstrow = &lds_a[row * ASTR + half * 128];
#pragma unroll
        for (int j = 0; j < 16; ++j)
            *(uint4*)(dstrow + j * 8) = *(const uint4*)(src + j * 8);
    }
    __syncthreads();

    int lane = t & 63;
    int wid = t >> 6;              // 4 waves, each owns 32 cols, all 128 rows
    int arow = lane & 15;
    int kq = lane >> 4;            // k-octet 0..3
    int col0 = n0 + wid * 32 + (lane & 15);
    int col1 = col0 + 16;
    const float* xb = x + (size_t)batch * CIN * S_;

    f32x4 acc[8][2] = {};

#pragma unroll
    for (int kk = 0; kk < 8; ++kk) {
        float f0[8], f1[8];
        const float* bp = xb + (size_t)(kk * 32 + kq * 8) * S_;
#pragma unroll
        for (int j = 0; j < 8; ++j) {
            f0[j] = bp[(size_t)j * S_ + col0];
            f1[j] = bp[(size_t)j * S_ + col1];
        }
        bf16x8 b0, b1;
#pragma unroll
        for (int j = 0; j < 8; ++j) {
            b0[j] = (short)f2bf(f0[j]);
            b1[j] = (short)f2bf(f1[j]);
        }
#pragma unroll
        for (int mf = 0; mf < 8; ++mf) {
            int row = mf * 16 + arow;
            bf16x8 a = *(const bf16x8*)&lds_a[row * ASTR + kk * 32 + kq * 8];
            acc[mf][0] = __builtin_amdgcn_mfma_f32_16x16x32_bf16(a, b0, acc[mf][0], 0, 0, 0);
            acc[mf][1] = __builtin_amdgcn_mfma_f32_16x16x32_bf16(a, b1, acc[mf][1], 0, 0, 0);
        }
    }

    // epilogue: D layout col=lane&15, row=(lane>>4)*4+r  (m89-verified)
#pragma unroll
    for (int mf = 0; mf < 8; ++mf) {
#pragma unroll
        for (int r = 0; r < 4; ++r) {
            int row = m0 + mf * 16 + (lane >> 4) * 4 + r;
            float bbv = bb[batch * COUT + row];
            size_t rb = (size_t)(batch * COUT + row) * S_;
#pragma unroll
            for (int nf = 0; nf < 2; ++nf) {
                int col = n0 + wid * 32 + nf * 16 + (lane & 15);
                out[rb + col] = acc[mf][nf][r] + bbv;
            }
        }
    }
}

// ---------------- K4: in-place LayerNorm(axis=S) + exact GELU ----------------
__global__ __launch_bounds__(256) void k_ln(float* __restrict__ y,
                                            const float* __restrict__ gamma,
                                            const float* __restrict__ beta) {
    size_t row = blockIdx.x;
    float* p = y + row * (size_t)S_;
    int t = threadIdx.x;
    float4 v[4];
    float s = 0.f, ss = 0.f;
#pragma unroll
    for (int j = 0; j < 4; ++j) {
        v[j] = *(const float4*)(p + (size_t)(j * 256 + t) * 4);
        s += v[j].x + v[j].y + v[j].z + v[j].w;
        ss += v[j].x * v[j].x + v[j].y * v[j].y + v[j].z * v[j].z + v[j].w * v[j].w;
    }
    for (int off = 32; off; off >>= 1) {
        s += __shfl_down(s, off);
        ss += __shfl_down(ss, off);
    }
    __shared__ float rs[4], rss[4];
    if ((t & 63) == 0) { rs[t >> 6] = s; rss[t >> 6] = ss; }
    __syncthreads();
    float S1 = rs[0] + rs[1] + rs[2] + rs[3];
    float S2 = rss[0] + rss[1] + rss[2] + rss[3];
    float mu = S1 * (1.f / S_);
    float var = S2 * (1.f / S_) - mu * mu;
    float rstd = rsqrtf(var + 1e-5f);
#pragma unroll
    for (int j = 0; j < 4; ++j) {
        size_t base = (size_t)(j * 256 + t) * 4;
        float4 g = *(const float4*)(gamma + base);
        float4 be = *(const float4*)(beta + base);
        float4 o;
        float z;
        z = (v[j].x - mu) * rstd * g.x + be.x; o.x = 0.5f * z * (1.f + erff(z * 0.70710678118f));
        z = (v[j].y - mu) * rstd * g.y + be.y; o.y = 0.5f * z * (1.f + erff(z * 0.70710678118f));
        z = (v[j].z - mu) * rstd * g.z + be.z; o.z = 0.5f * z * (1.f + erff(z * 0.70710678118f));
        z = (v[j].w - mu) * rstd * g.w + be.w; o.w = 0.5f * z * (1.f + erff(z * 0.70710678118f));
        *(float4*)(p + base) = o;
    }
}

extern "C" void kernel_launch(void* const* d_in, const int* in_sizes, int n_in,
                              void* d_out, int out_size, void* d_ws, size_t ws_size,
                              hipStream_t stream) {
    const float* x      = (const float*)d_in[0];
    const float* w1     = (const float*)d_in[1];
    const float* w2     = (const float*)d_in[2];
    const float* b2     = (const float*)d_in[3];
    const float* conv_w = (const float*)d_in[4];
    const float* conv_b = (const float*)d_in[5];
    const float* gamma  = (const float*)d_in[6];
    const float* beta   = (const float*)d_in[7];
    float* out = (float*)d_out;

    float* pooled = (float*)d_ws;                              // 64*256*4   = 64 KiB
    float* att    = (float*)((char*)d_ws + 65536);             // 64*4*4     = 1 KiB
    float* bb     = (float*)((char*)d_ws + 66560);             // 64*512*4   = 128 KiB
    unsigned short* wb = (unsigned short*)((char*)d_ws + 262144); // 64*512*256*2 = 16 MiB

    k_pool<<<B_ * CIN, 256, 0, stream>>>(x, pooled);
    k_att<<<B_, 64, 0, stream>>>(pooled, w1, w2, b2, conv_b, att, bb);
    k_wb<<<B_ * 32, 256, 0, stream>>>(conv_w, att, wb);
    k_gemm<<<B_ * 128, 256, 0, stream>>>(x, wb, bb, out);
    k_ln<<<B_ * COUT, 256, 0, stream>>>(out, gamma, beta);
}